// Round 1
// baseline (1218.052 us; speedup 1.0000x reference)
//
#include <hip/hip_runtime.h>
#include <math.h>

// Problem constants (fixed by reference)
#define DIMD 256
#define KCODES 4096
#define NROWS 65536
#define QN (NROWS * DIMD)   // 16777216 quantized elements

// ---------------- pass1 (bf16 MFMA prune) parameters ----------------
constexpr int P1_BM = 64;      // rows per block
constexpr int P1_BN = 128;     // codes per N-tile
constexpr int NT    = KCODES / P1_BN;   // 32 N-tiles
constexpr int AST2  = 264;     // As row stride in bf16 elems (528 B)
constexpr int BST   = 40;      // Bs row stride in bf16 elems (80 B)
// Dot-scale margin: candidate iff dot > running_max_row - TAU2.
// Error stack (dot scale): bf16 operand rounding <=2.3e-4 (worst), np fp32
// quantization ~3e-5, dropped se <=0.8e-5  ->  TAU2 = 7.5e-4 is ~2.8x margin.
// Single-pass note: threshold uses the PREFIX max (running max including the
// current tile), which is <= final max -> collected set is a SUPERSET of the
// final-max candidate set. Pass2 re-ranks exactly, so superset is safe.
// E[cands] ~ 2*H(2048) + tau-window ~ 20; P(>CAP) ~ 1e-7/row, overflow -> fallback.
constexpr float TAU2 = 7.5e-4f;
constexpr int CAP   = 48;      // candidate slots per row (overflow -> exact fallback)

typedef __attribute__((ext_vector_type(8))) short bf16x8;
typedef __attribute__((ext_vector_type(4))) float f32x4;

// RNE float -> bf16 bits (inputs finite; no NaN handling needed)
__device__ __forceinline__ unsigned short f2bf(float f) {
    unsigned int u = __builtin_bit_cast(unsigned int, f);
    u += 0x7fffu + ((u >> 16) & 1u);
    return (unsigned short)(u >> 16);
}

// Opaque barrier: forces v to be a rounded fp32 value (blocks FMA contraction)
__device__ __forceinline__ float opaque(float v) {
    asm volatile("" : "+v"(v));
    return v;
}

// numpy pairwise_sum of 256 fp32 squares, bit-exact replication (validated R4)
__device__ __forceinline__ float np_sumsq_256(const float* __restrict__ p) {
    float total = 0.0f;
    #pragma unroll
    for (int half = 0; half < 2; ++half) {
        const float* b = p + half * 128;
        float r[8];
        #pragma unroll
        for (int j = 0; j < 8; ++j) {
            const float v = b[j];
            r[j] = opaque(v * v);
        }
        for (int i = 8; i < 128; i += 8) {
            #pragma unroll
            for (int j = 0; j < 8; ++j) {
                const float v = b[i + j];
                r[j] += opaque(v * v);
            }
        }
        const float res = ((r[0] + r[1]) + (r[2] + r[3])) + ((r[4] + r[5]) + (r[6] + r[7]));
        total = (half == 0) ? res : (total + res);
    }
    return total;
}

// ---------------------------------------------------------------- kernel Sx
__global__ void sx_kernel(const float* __restrict__ x, float* __restrict__ sx) {
    const int row = blockIdx.x * blockDim.x + threadIdx.x;
    sx[row] = np_sumsq_256(x + (size_t)row * DIMD);
}

// ---------------------------------------------------------------- kernel Se
__global__ void se_kernel(const float* __restrict__ emb, float* __restrict__ se) {
    const int k = blockIdx.x * blockDim.x + threadIdx.x;
    se[k] = np_sumsq_256(emb + (size_t)k * DIMD);
}

// ---------------------------------------------------------------- conv emb->bf16
__global__ void conv_emb_kernel(const float* __restrict__ emb, unsigned short* __restrict__ embh) {
    const int i = blockIdx.x * blockDim.x + threadIdx.x;  // float4 index
    const float4 v = ((const float4*)emb)[i];
    ushort4 h;
    h.x = f2bf(v.x); h.y = f2bf(v.y); h.z = f2bf(v.z); h.w = f2bf(v.w);
    ((ushort4*)embh)[i] = h;
}

// ---------------------------------------------------------------- kernel P1
// Single-pass bf16 MFMA prune: per tile, update the per-row running max dot
// (cross-lane reduce stays inside the 16-lane quad group -> DPP, no DS pipe),
// then collect codes with dot > running_max - TAU2. Running max only grows,
// so the collected set is a superset of the exact final candidate set.
__global__ __launch_bounds__(256, 3)
void pass1_kernel(const float* __restrict__ x, const unsigned short* __restrict__ embh,
                  int* __restrict__ cand, int* __restrict__ cnt_out) {
    __shared__ unsigned short As[P1_BM * AST2];   // 33792 B : x rows, bf16, full K=256
    __shared__ unsigned short Bs[P1_BN * BST];    // 10240 B : emb chunk (32 k), bf16
    __shared__ int   cnts[P1_BM];

    const int t    = threadIdx.x;
    const int w    = t >> 6;
    const int lane = t & 63;
    const int quad = lane >> 4;
    const int lm   = lane & 15;
    const int rbase = (w >> 1) * 32;   // wave row offset (2 row-groups)
    const int cbase = (w & 1) * 64;    // wave col offset (2 col-groups)
    const int row0 = blockIdx.x * P1_BM;

    if (t < P1_BM) cnts[t] = 0;

    // stage A once: rows row0..row0+63, fp32 -> bf16. thread: row t>>2, elems (t&3)*4 + 16j
    {
        const int r = t >> 2, cc = (t & 3) * 4;
        const float* xp = x + (size_t)(row0 + r) * DIMD + cc;
        unsigned short* dst = &As[r * AST2 + cc];
        #pragma unroll
        for (int j = 0; j < 16; ++j) {
            const float4 v = *(const float4*)(xp + 16 * j);
            ushort4 h;
            h.x = f2bf(v.x); h.y = f2bf(v.y); h.z = f2bf(v.z); h.w = f2bf(v.w);
            *(ushort4*)(dst + 16 * j) = h;
        }
    }
    __syncthreads();

    float rm[2][4];
    #pragma unroll
    for (int f = 0; f < 2; ++f)
        #pragma unroll
        for (int reg = 0; reg < 4; ++reg) rm[f][reg] = -INFINITY;

    for (int tile = 0; tile < NT; ++tile) {
        const int c0 = tile * P1_BN;
        f32x4 acc[2][4];
        #pragma unroll
        for (int f = 0; f < 2; ++f)
            #pragma unroll
            for (int g = 0; g < 4; ++g) acc[f][g] = (f32x4){0.f, 0.f, 0.f, 0.f};

        for (int ck = 0; ck < 8; ++ck) {
            const int k0 = ck * 32;
            __syncthreads();  // protect Bs from previous readers
            {
                const int cr = t >> 1, kk = (t & 1) * 16;
                const unsigned short* ep = embh + (size_t)(c0 + cr) * DIMD + k0 + kk;
                unsigned short* dst = &Bs[cr * BST + kk];
                const uint4 p0 = *(const uint4*)(ep);
                const uint4 p1 = *(const uint4*)(ep + 8);
                *(uint4*)(dst) = p0;
                *(uint4*)(dst + 8) = p1;
            }
            __syncthreads();

            bf16x8 a[2], b[4];
            #pragma unroll
            for (int f = 0; f < 2; ++f)
                a[f] = *(const bf16x8*)&As[(rbase + f * 16 + lm) * AST2 + k0 + quad * 8];
            #pragma unroll
            for (int g = 0; g < 4; ++g)
                b[g] = *(const bf16x8*)&Bs[(cbase + g * 16 + lm) * BST + quad * 8];
            #pragma unroll
            for (int f = 0; f < 2; ++f)
                #pragma unroll
                for (int g = 0; g < 4; ++g)
                    acc[f][g] = __builtin_amdgcn_mfma_f32_16x16x32_bf16(a[f], b[g], acc[f][g], 0, 0, 0);
        }

        // epilogue: update running per-row max (tile-inclusive), then collect
        #pragma unroll
        for (int f = 0; f < 2; ++f)
            #pragma unroll
            for (int reg = 0; reg < 4; ++reg) {
                float mm = fmaxf(fmaxf(acc[f][0][reg], acc[f][1][reg]),
                                 fmaxf(acc[f][2][reg], acc[f][3][reg]));
                #pragma unroll
                for (int off = 1; off < 16; off <<= 1)
                    mm = fmaxf(mm, __shfl_xor(mm, off, 64));   // stays within quad (DPP)
                rm[f][reg] = fmaxf(rm[f][reg], mm);
                const float thr = rm[f][reg] - TAU2;
                const int r = rbase + f * 16 + quad * 4 + reg;
                #pragma unroll
                for (int g = 0; g < 4; ++g) {
                    if (acc[f][g][reg] > thr) {
                        const int slot = atomicAdd(&cnts[r], 1);
                        if (slot < CAP)
                            cand[(size_t)(row0 + r) * CAP + slot] = c0 + cbase + g * 16 + lm;
                    }
                }
            }
    }
    __syncthreads();
    if (t < P1_BM) cnt_out[row0 + t] = (cnts[t] > CAP) ? -1 : cnts[t];
}

// ---------------------------------------------------------------- kernel P2
// Exact np-semantics re-rank of candidates: dist = fl(fl(sx - 2*dot) + se),
// dot = sequential fp32 FMA chain (validated R5/R6). One wave per row.
__global__ void pass2_kernel(const float* __restrict__ x, const float* __restrict__ emb,
                             const float* __restrict__ sx, const float* __restrict__ se,
                             const int* __restrict__ cand, const int* __restrict__ cnt,
                             int* __restrict__ out_idx) {
    const int w = threadIdx.x >> 6, lane = threadIdx.x & 63;
    const int row = blockIdx.x * 4 + w;
    const int n = cnt[row];
    const float sxr = sx[row];
    const float* xp = x + (size_t)row * DIMD;

    float bestd = INFINITY;
    int   bestc = 0x7fffffff;

    if (n >= 1 && n <= CAP) {
        if (lane < n) {
            const int code = cand[(size_t)row * CAP + lane];
            const float* ep = emb + (size_t)code * DIMD;
            float a = 0.0f;
            for (int d4 = 0; d4 < DIMD / 4; ++d4) {
                const float4 xv = ((const float4*)xp)[d4];
                const float4 ev = ((const float4*)ep)[d4];
                a = fmaf(xv.x, ev.x, a);
                a = fmaf(xv.y, ev.y, a);
                a = fmaf(xv.z, ev.z, a);
                a = fmaf(xv.w, ev.w, a);
            }
            const float t1 = sxr - 2.0f * a;   // fl(sx - 2*dot)
            bestd = t1 + se[code];             // fl(t1 + se)
            bestc = code;
        }
    } else {
        // overflow / safety fallback: full exact scan (ascending per lane)
        for (int c = lane; c < KCODES; c += 64) {
            const float* ep = emb + (size_t)c * DIMD;
            float a = 0.0f;
            for (int d4 = 0; d4 < DIMD / 4; ++d4) {
                const float4 xv = ((const float4*)xp)[d4];
                const float4 ev = ((const float4*)ep)[d4];
                a = fmaf(xv.x, ev.x, a);
                a = fmaf(xv.y, ev.y, a);
                a = fmaf(xv.z, ev.z, a);
                a = fmaf(xv.w, ev.w, a);
            }
            const float t1 = sxr - 2.0f * a;
            const float dd = t1 + se[c];
            if (dd < bestd || (dd == bestd && c < bestc)) { bestd = dd; bestc = c; }
        }
    }
    // wave argmin, lexicographic (value, code): np first-occurrence semantics
    #pragma unroll
    for (int off = 32; off > 0; off >>= 1) {
        const float od = __shfl_down(bestd, off, 64);
        const int   oc = __shfl_down(bestc, off, 64);
        if (od < bestd || (od == bestd && oc < bestc)) { bestd = od; bestc = oc; }
    }
    if (lane == 0) out_idx[row] = bestc;
}

// ---------------------------------------------------------------- kernel C
// gather emb[idx] -> quantized, write indices as float, per-block partial loss.
// (No same-address atomics: 16384 serialized TCC RMWs replaced by partial[] +
//  a one-block tree reduction.)
__global__ void gather_loss_kernel(const float* __restrict__ x, const float* __restrict__ emb,
                                   const int* __restrict__ idxs, float* __restrict__ out,
                                   float* __restrict__ partial) {
    const int w = threadIdx.x >> 6, lane = threadIdx.x & 63;
    const int row = blockIdx.x * 4 + w;
    const int idx = idxs[row];
    const float4 e4 = ((const float4*)(emb + (size_t)idx * DIMD))[lane];
    const float4 x4 = ((const float4*)(x + (size_t)row * DIMD))[lane];
    ((float4*)(out + (size_t)row * DIMD))[lane] = e4;
    const float dx = e4.x - x4.x, dy = e4.y - x4.y, dz = e4.z - x4.z, dw = e4.w - x4.w;
    float s = dx * dx + dy * dy + dz * dz + dw * dw;
    #pragma unroll
    for (int off = 32; off > 0; off >>= 1) s += __shfl_down(s, off, 64);
    __shared__ float wsum[4];
    if (lane == 0) wsum[w] = s;
    __syncthreads();
    if (threadIdx.x == 0)
        partial[blockIdx.x] = wsum[0] + wsum[1] + wsum[2] + wsum[3];
    if (lane == 0) out[QN + 1 + row] = (float)idx;
}

// ---------------------------------------------------------------- kernel L
// reduce 16384 per-block partials -> loss (double accum: deterministic, and
// strictly more accurate than the previous racy fp32 atomic chain)
__global__ void loss_reduce_kernel(const float* __restrict__ partial, float* __restrict__ out) {
    const int t = threadIdx.x;           // 256 threads, 1 block
    const int lane = t & 63, w = t >> 6;
    double s = 0.0;
    for (int i = t; i < NROWS / 4; i += 256) s += (double)partial[i];
    #pragma unroll
    for (int off = 32; off > 0; off >>= 1) {
        s += __shfl_down((float)0.0f, 0, 64) * 0.0;  // no-op keep layout simple
        const double hi = __builtin_bit_cast(double,
            ((unsigned long long)__shfl_down((unsigned int)(__builtin_bit_cast(unsigned long long, s) >> 32), off, 64) << 32) |
             (unsigned long long)__shfl_down((unsigned int)(__builtin_bit_cast(unsigned long long, s) & 0xffffffffull), off, 64));
        s += hi;
    }
    __shared__ double wsum[4];
    if (lane == 0) wsum[w] = s;
    __syncthreads();
    if (t == 0) {
        const double tot = wsum[0] + wsum[1] + wsum[2] + wsum[3];
        out[QN] = (float)(tot * (1.25 / (double)QN));
    }
}

// ---------------------------------------------------------------- launcher
extern "C" void kernel_launch(void* const* d_in, const int* in_sizes, int n_in,
                              void* d_out, int out_size, void* d_ws, size_t ws_size,
                              hipStream_t stream) {
    const float* x   = (const float*)d_in[0];   // [65536, 256]
    const float* emb = (const float*)d_in[1];   // [4096, 256]
    float* out = (float*)d_out;                 // q[16777216] | loss[1] | idx[65536]

    char* ws = (char*)d_ws;
    unsigned short* embh = (unsigned short*)ws;           ws += (size_t)KCODES * DIMD * 2; // 2 MB
    float* sx  = (float*)ws;                              ws += (size_t)NROWS * 4;         // 256 KB
    float* se  = (float*)ws;                              ws += (size_t)KCODES * 4;        // 16 KB
    int*   cand = (int*)ws;                               ws += (size_t)NROWS * CAP * 4;   // 12.6 MB
    int*   cnt  = (int*)ws;                               ws += (size_t)NROWS * 4;         // 256 KB
    int*   idx  = (int*)ws;                               ws += (size_t)NROWS * 4;         // 256 KB
    float* partial = (float*)ws;                                                           // 64 KB

    conv_emb_kernel<<<KCODES * DIMD / 4 / 256, 256, 0, stream>>>(emb, embh);
    sx_kernel<<<NROWS / 256, 256, 0, stream>>>(x, sx);
    se_kernel<<<KCODES / 256, 256, 0, stream>>>(emb, se);
    pass1_kernel<<<NROWS / P1_BM, 256, 0, stream>>>(x, embh, cand, cnt);
    pass2_kernel<<<NROWS / 4, 256, 0, stream>>>(x, emb, sx, se, cand, cnt, idx);
    gather_loss_kernel<<<NROWS / 4, 256, 0, stream>>>(x, emb, idx, out, partial);
    loss_reduce_kernel<<<1, 256, 0, stream>>>(partial, out);
}

// Round 3
// 1145.553 us; speedup vs baseline: 1.0633x; 1.0633x over previous
//
#include <hip/hip_runtime.h>
#include <math.h>

// Problem constants (fixed by reference)
#define DIMD 256
#define KCODES 4096
#define NROWS 65536
#define QN (NROWS * DIMD)   // 16777216 quantized elements

// ---------------- pass1 (bf16 MFMA prune) parameters ----------------
constexpr int P1_BM = 64;      // rows per block
constexpr int P1_BN = 128;     // codes per N-tile
constexpr int NT    = KCODES / P1_BN;   // 32 N-tiles
constexpr int AST2  = 264;     // As row stride in bf16 elems (528 B)
constexpr int BST   = 40;      // Bs row stride in bf16 elems (80 B)
// Dot-scale margin: candidate iff dot > running_max_row - TAU2.
// Error stack (dot scale): bf16 operand rounding <=2.3e-4 (worst), np fp32
// quantization ~3e-5, dropped se <=0.8e-5  ->  TAU2 = 7.5e-4 is ~2.8x margin.
// Single-pass note: threshold uses the PREFIX max (running max including the
// current tile), which is <= final max -> collected set is a SUPERSET of the
// final-max candidate set (E ~ 20/row). Each stored word also carries the
// MFMA dot (top-20 fp32 bits), so pass2 can recover the FINAL max and
// re-filter down to the exact two-pass candidate set (~3.5/row) before the
// expensive exact re-rank. Truncation error of the 20-bit key is < 2e-6
// (dot scale), covered by inflating the pass2 margin by 1e-5.
constexpr float TAU2 = 7.5e-4f;
constexpr float TAU2B = TAU2 + 1e-5f;   // pass2 re-filter margin (key truncation)
constexpr int CAP   = 48;      // candidate slots per row (overflow -> exact fallback)

typedef __attribute__((ext_vector_type(8))) short bf16x8;
typedef __attribute__((ext_vector_type(4))) float f32x4;

// RNE float -> bf16 bits (inputs finite; no NaN handling needed)
__device__ __forceinline__ unsigned short f2bf(float f) {
    unsigned int u = __builtin_bit_cast(unsigned int, f);
    u += 0x7fffu + ((u >> 16) & 1u);
    return (unsigned short)(u >> 16);
}

// Opaque barrier: forces v to be a rounded fp32 value (blocks FMA contraction)
__device__ __forceinline__ float opaque(float v) {
    asm volatile("" : "+v"(v));
    return v;
}

// numpy pairwise_sum of 256 fp32 squares, bit-exact replication (validated R4)
__device__ __forceinline__ float np_sumsq_256(const float* __restrict__ p) {
    float total = 0.0f;
    #pragma unroll
    for (int half = 0; half < 2; ++half) {
        const float* b = p + half * 128;
        float r[8];
        #pragma unroll
        for (int j = 0; j < 8; ++j) {
            const float v = b[j];
            r[j] = opaque(v * v);
        }
        for (int i = 8; i < 128; i += 8) {
            #pragma unroll
            for (int j = 0; j < 8; ++j) {
                const float v = b[i + j];
                r[j] += opaque(v * v);
            }
        }
        const float res = ((r[0] + r[1]) + (r[2] + r[3])) + ((r[4] + r[5]) + (r[6] + r[7]));
        total = (half == 0) ? res : (total + res);
    }
    return total;
}

// ---------------------------------------------------------------- kernel Sx
__global__ void sx_kernel(const float* __restrict__ x, float* __restrict__ sx) {
    const int row = blockIdx.x * blockDim.x + threadIdx.x;
    sx[row] = np_sumsq_256(x + (size_t)row * DIMD);
}

// ---------------------------------------------------------------- kernel Se
__global__ void se_kernel(const float* __restrict__ emb, float* __restrict__ se) {
    const int k = blockIdx.x * blockDim.x + threadIdx.x;
    se[k] = np_sumsq_256(emb + (size_t)k * DIMD);
}

// ---------------------------------------------------------------- conv emb->bf16
__global__ void conv_emb_kernel(const float* __restrict__ emb, unsigned short* __restrict__ embh) {
    const int i = blockIdx.x * blockDim.x + threadIdx.x;  // float4 index
    const float4 v = ((const float4*)emb)[i];
    ushort4 h;
    h.x = f2bf(v.x); h.y = f2bf(v.y); h.z = f2bf(v.z); h.w = f2bf(v.w);
    ((ushort4*)embh)[i] = h;
}

// ---------------------------------------------------------------- kernel P1
// Single-pass bf16 MFMA prune: per tile, update the per-row running max dot
// (cross-lane reduce stays inside the 16-lane quad group -> DPP, no DS pipe),
// then collect codes with dot > running_max - TAU2. Stored word packs the
// dot's top-20 fp32 bits with the 12-bit code so pass2 can re-filter against
// the FINAL max without recomputing anything.
__global__ __launch_bounds__(256, 3)
void pass1_kernel(const float* __restrict__ x, const unsigned short* __restrict__ embh,
                  unsigned int* __restrict__ cand, int* __restrict__ cnt_out) {
    __shared__ unsigned short As[P1_BM * AST2];   // 33792 B : x rows, bf16, full K=256
    __shared__ unsigned short Bs[P1_BN * BST];    // 10240 B : emb chunk (32 k), bf16
    __shared__ int   cnts[P1_BM];

    const int t    = threadIdx.x;
    const int w    = t >> 6;
    const int lane = t & 63;
    const int quad = lane >> 4;
    const int lm   = lane & 15;
    const int rbase = (w >> 1) * 32;   // wave row offset (2 row-groups)
    const int cbase = (w & 1) * 64;    // wave col offset (2 col-groups)
    const int row0 = blockIdx.x * P1_BM;

    if (t < P1_BM) cnts[t] = 0;

    // stage A once: rows row0..row0+63, fp32 -> bf16. thread: row t>>2, elems (t&3)*4 + 16j
    {
        const int r = t >> 2, cc = (t & 3) * 4;
        const float* xp = x + (size_t)(row0 + r) * DIMD + cc;
        unsigned short* dst = &As[r * AST2 + cc];
        #pragma unroll
        for (int j = 0; j < 16; ++j) {
            const float4 v = *(const float4*)(xp + 16 * j);
            ushort4 h;
            h.x = f2bf(v.x); h.y = f2bf(v.y); h.z = f2bf(v.z); h.w = f2bf(v.w);
            *(ushort4*)(dst + 16 * j) = h;
        }
    }
    __syncthreads();

    float rm[2][4];
    #pragma unroll
    for (int f = 0; f < 2; ++f)
        #pragma unroll
        for (int reg = 0; reg < 4; ++reg) rm[f][reg] = -INFINITY;

    for (int tile = 0; tile < NT; ++tile) {
        const int c0 = tile * P1_BN;
        f32x4 acc[2][4];
        #pragma unroll
        for (int f = 0; f < 2; ++f)
            #pragma unroll
            for (int g = 0; g < 4; ++g) acc[f][g] = (f32x4){0.f, 0.f, 0.f, 0.f};

        for (int ck = 0; ck < 8; ++ck) {
            const int k0 = ck * 32;
            __syncthreads();  // protect Bs from previous readers
            {
                const int cr = t >> 1, kk = (t & 1) * 16;
                const unsigned short* ep = embh + (size_t)(c0 + cr) * DIMD + k0 + kk;
                unsigned short* dst = &Bs[cr * BST + kk];
                const uint4 p0 = *(const uint4*)(ep);
                const uint4 p1 = *(const uint4*)(ep + 8);
                *(uint4*)(dst) = p0;
                *(uint4*)(dst + 8) = p1;
            }
            __syncthreads();

            bf16x8 a[2], b[4];
            #pragma unroll
            for (int f = 0; f < 2; ++f)
                a[f] = *(const bf16x8*)&As[(rbase + f * 16 + lm) * AST2 + k0 + quad * 8];
            #pragma unroll
            for (int g = 0; g < 4; ++g)
                b[g] = *(const bf16x8*)&Bs[(cbase + g * 16 + lm) * BST + quad * 8];
            #pragma unroll
            for (int f = 0; f < 2; ++f)
                #pragma unroll
                for (int g = 0; g < 4; ++g)
                    acc[f][g] = __builtin_amdgcn_mfma_f32_16x16x32_bf16(a[f], b[g], acc[f][g], 0, 0, 0);
        }

        // epilogue: update running per-row max (tile-inclusive), then collect
        #pragma unroll
        for (int f = 0; f < 2; ++f)
            #pragma unroll
            for (int reg = 0; reg < 4; ++reg) {
                float mm = fmaxf(fmaxf(acc[f][0][reg], acc[f][1][reg]),
                                 fmaxf(acc[f][2][reg], acc[f][3][reg]));
                #pragma unroll
                for (int off = 1; off < 16; off <<= 1)
                    mm = fmaxf(mm, __shfl_xor(mm, off, 64));   // stays within quad (DPP)
                rm[f][reg] = fmaxf(rm[f][reg], mm);
                const float thr = rm[f][reg] - TAU2;
                const int r = rbase + f * 16 + quad * 4 + reg;
                #pragma unroll
                for (int g = 0; g < 4; ++g) {
                    const float dv = acc[f][g][reg];
                    if (dv > thr) {
                        const int slot = atomicAdd(&cnts[r], 1);
                        if (slot < CAP) {
                            // pack: top-20 fp32 bits of dot (clamped >=0, so
                            // uint compare == float compare; clamp degrades
                            // safely to "keep everything") | 12-bit code
                            const unsigned int ub =
                                __builtin_bit_cast(unsigned int, fmaxf(dv, 0.0f));
                            const unsigned int word =
                                (ub & 0xFFFFF000u) | (unsigned int)(c0 + cbase + g * 16 + lm);
                            cand[(size_t)(row0 + r) * CAP + slot] = word;
                        }
                    }
                }
            }
    }
    __syncthreads();
    if (t < P1_BM) cnt_out[row0 + t] = (cnts[t] > CAP) ? -1 : cnts[t];
}

// ---------------------------------------------------------------- kernel P2
// Re-filter stored candidates against the FINAL max dot (present among the
// stored keys: the argmax code always passes the prefix threshold), then run
// the exact np-semantics re-rank only on the survivors (~3.5/row):
// dist = fl(fl(sx - 2*dot) + se), dot = sequential fp32 FMA chain
// (validated R5/R6). One wave per row.
__global__ void pass2_kernel(const float* __restrict__ x, const float* __restrict__ emb,
                             const float* __restrict__ sx, const float* __restrict__ se,
                             const unsigned int* __restrict__ cand, const int* __restrict__ cnt,
                             int* __restrict__ out_idx) {
    const int w = threadIdx.x >> 6, lane = threadIdx.x & 63;
    const int row = blockIdx.x * 4 + w;
    const int n = cnt[row];
    const float sxr = sx[row];
    const float* xp = x + (size_t)row * DIMD;

    float bestd = INFINITY;
    int   bestc = 0x7fffffff;

    if (n >= 1 && n <= CAP) {
        float dtil = -INFINITY;
        int   code = 0;
        if (lane < n) {
            const unsigned int word = cand[(size_t)row * CAP + lane];
            dtil = __builtin_bit_cast(float, word & 0xFFFFF000u);
            code = (int)(word & 0xFFFu);
        }
        // wave max of stored (truncated) dots == final max - O(2e-6)
        float mx = dtil;
        #pragma unroll
        for (int off = 1; off < 64; off <<= 1)
            mx = fmaxf(mx, __shfl_xor(mx, off, 64));
        const bool active = (lane < n) && (dtil > mx - TAU2B);
        if (active) {
            const float* ep = emb + (size_t)code * DIMD;
            float a = 0.0f;
            for (int d4 = 0; d4 < DIMD / 4; ++d4) {
                const float4 xv = ((const float4*)xp)[d4];
                const float4 ev = ((const float4*)ep)[d4];
                a = fmaf(xv.x, ev.x, a);
                a = fmaf(xv.y, ev.y, a);
                a = fmaf(xv.z, ev.z, a);
                a = fmaf(xv.w, ev.w, a);
            }
            const float t1 = sxr - 2.0f * a;   // fl(sx - 2*dot)
            bestd = t1 + se[code];             // fl(t1 + se)
            bestc = code;
        }
    } else {
        // overflow / safety fallback: full exact scan (ascending per lane)
        for (int c = lane; c < KCODES; c += 64) {
            const float* ep = emb + (size_t)c * DIMD;
            float a = 0.0f;
            for (int d4 = 0; d4 < DIMD / 4; ++d4) {
                const float4 xv = ((const float4*)xp)[d4];
                const float4 ev = ((const float4*)ep)[d4];
                a = fmaf(xv.x, ev.x, a);
                a = fmaf(xv.y, ev.y, a);
                a = fmaf(xv.z, ev.z, a);
                a = fmaf(xv.w, ev.w, a);
            }
            const float t1 = sxr - 2.0f * a;
            const float dd = t1 + se[c];
            if (dd < bestd || (dd == bestd && c < bestc)) { bestd = dd; bestc = c; }
        }
    }
    // wave argmin, lexicographic (value, code): np first-occurrence semantics
    #pragma unroll
    for (int off = 32; off > 0; off >>= 1) {
        const float od = __shfl_down(bestd, off, 64);
        const int   oc = __shfl_down(bestc, off, 64);
        if (od < bestd || (od == bestd && oc < bestc)) { bestd = od; bestc = oc; }
    }
    if (lane == 0) out_idx[row] = bestc;
}

// ---------------------------------------------------------------- kernel C
// gather emb[idx] -> quantized, write indices as float, per-block partial loss.
__global__ void gather_loss_kernel(const float* __restrict__ x, const float* __restrict__ emb,
                                   const int* __restrict__ idxs, float* __restrict__ out,
                                   float* __restrict__ partial) {
    const int w = threadIdx.x >> 6, lane = threadIdx.x & 63;
    const int row = blockIdx.x * 4 + w;
    const int idx = idxs[row];
    const float4 e4 = ((const float4*)(emb + (size_t)idx * DIMD))[lane];
    const float4 x4 = ((const float4*)(x + (size_t)row * DIMD))[lane];
    ((float4*)(out + (size_t)row * DIMD))[lane] = e4;
    const float dx = e4.x - x4.x, dy = e4.y - x4.y, dz = e4.z - x4.z, dw = e4.w - x4.w;
    float s = dx * dx + dy * dy + dz * dz + dw * dw;
    #pragma unroll
    for (int off = 32; off > 0; off >>= 1) s += __shfl_down(s, off, 64);
    __shared__ float wsum[4];
    if (lane == 0) wsum[w] = s;
    __syncthreads();
    if (threadIdx.x == 0)
        partial[blockIdx.x] = wsum[0] + wsum[1] + wsum[2] + wsum[3];
    if (lane == 0) out[QN + 1 + row] = (float)idx;
}

// ---------------------------------------------------------------- kernel L
// reduce 16384 per-block partials -> loss (LDS tree, double accum:
// deterministic, strictly more accurate than a racy fp32 atomic chain)
__global__ void loss_reduce_kernel(const float* __restrict__ partial, float* __restrict__ out) {
    const int t = threadIdx.x;           // 256 threads, 1 block
    double s = 0.0;
    for (int i = t; i < NROWS / 4; i += 256) s += (double)partial[i];
    __shared__ double tsum[256];
    tsum[t] = s;
    __syncthreads();
    #pragma unroll
    for (int off = 128; off > 0; off >>= 1) {
        if (t < off) tsum[t] += tsum[t + off];
        __syncthreads();
    }
    if (t == 0) out[QN] = (float)(tsum[0] * (1.25 / (double)QN));
}

// ---------------------------------------------------------------- launcher
extern "C" void kernel_launch(void* const* d_in, const int* in_sizes, int n_in,
                              void* d_out, int out_size, void* d_ws, size_t ws_size,
                              hipStream_t stream) {
    const float* x   = (const float*)d_in[0];   // [65536, 256]
    const float* emb = (const float*)d_in[1];   // [4096, 256]
    float* out = (float*)d_out;                 // q[16777216] | loss[1] | idx[65536]

    char* ws = (char*)d_ws;
    unsigned short* embh = (unsigned short*)ws;           ws += (size_t)KCODES * DIMD * 2; // 2 MB
    float* sx  = (float*)ws;                              ws += (size_t)NROWS * 4;         // 256 KB
    float* se  = (float*)ws;                              ws += (size_t)KCODES * 4;        // 16 KB
    unsigned int* cand = (unsigned int*)ws;               ws += (size_t)NROWS * CAP * 4;   // 12.6 MB
    int*   cnt  = (int*)ws;                               ws += (size_t)NROWS * 4;         // 256 KB
    int*   idx  = (int*)ws;                               ws += (size_t)NROWS * 4;         // 256 KB
    float* partial = (float*)ws;                                                           // 64 KB

    conv_emb_kernel<<<KCODES * DIMD / 4 / 256, 256, 0, stream>>>(emb, embh);
    sx_kernel<<<NROWS / 256, 256, 0, stream>>>(x, sx);
    se_kernel<<<KCODES / 256, 256, 0, stream>>>(emb, se);
    pass1_kernel<<<NROWS / P1_BM, 256, 0, stream>>>(x, embh, cand, cnt);
    pass2_kernel<<<NROWS / 4, 256, 0, stream>>>(x, emb, sx, se, cand, cnt, idx);
    gather_loss_kernel<<<NROWS / 4, 256, 0, stream>>>(x, emb, idx, out, partial);
    loss_reduce_kernel<<<1, 256, 0, stream>>>(partial, out);
}

// Round 4
// 1050.351 us; speedup vs baseline: 1.1597x; 1.0906x over previous
//
#include <hip/hip_runtime.h>
#include <math.h>

// Problem constants (fixed by reference)
#define DIMD 256
#define KCODES 4096
#define NROWS 65536
#define QN (NROWS * DIMD)   // 16777216 quantized elements

// ---------------- pass1 (bf16 MFMA prune) parameters ----------------
constexpr int P1_BM = 64;      // rows per block
constexpr int P1_BN = 128;     // codes per N-tile
constexpr int NT    = KCODES / P1_BN;   // 32 N-tiles
// Dot-scale margin: candidate iff dot > running_global_prefix_max - TAU2.
// Error stack (dot scale): bf16 operand rounding <=2.3e-4 (worst), np fp32
// quantization ~3e-5, dropped se <=0.8e-5  ->  TAU2 = 7.5e-4 is ~2.8x margin.
// Prefix max (tile-inclusive, merged across all 4 waves) <= final max at
// every collection point -> collected set is a SUPERSET of the final-max
// candidate set (E ~ 7/row). Stored word packs the MFMA dot (top-20 fp32
// bits) with the 12-bit code so pass2 recovers the FINAL max and re-filters
// to ~3.5/row before the exact re-rank. Key truncation < 2.5e-6 covered by
// the +1e-5 pass2 margin.
constexpr float TAU2 = 7.5e-4f;
constexpr float TAU2B = TAU2 + 1e-5f;   // pass2 re-filter margin (key truncation)
constexpr int CAP   = 48;      // candidate slots per row (overflow -> exact fallback)

typedef __attribute__((ext_vector_type(8))) short bf16x8;
typedef __attribute__((ext_vector_type(4))) float f32x4;

// RNE float -> bf16 bits (inputs finite; no NaN handling needed)
__device__ __forceinline__ unsigned short f2bf(float f) {
    unsigned int u = __builtin_bit_cast(unsigned int, f);
    u += 0x7fffu + ((u >> 16) & 1u);
    return (unsigned short)(u >> 16);
}

// Opaque barrier: forces v to be a rounded fp32 value (blocks FMA contraction)
__device__ __forceinline__ float opaque(float v) {
    asm volatile("" : "+v"(v));
    return v;
}

// async global->LDS, 16 B per lane, dest = wave-uniform base + lane*16
__device__ __forceinline__ void gload_lds16(const void* g, void* l) {
    __builtin_amdgcn_global_load_lds(
        (const __attribute__((address_space(1))) unsigned int*)g,
        (__attribute__((address_space(3))) unsigned int*)l, 16, 0, 0);
}

// numpy pairwise_sum of 256 fp32 squares, bit-exact replication (validated R4)
__device__ __forceinline__ float np_sumsq_256(const float* __restrict__ p) {
    float total = 0.0f;
    #pragma unroll
    for (int half = 0; half < 2; ++half) {
        const float* b = p + half * 128;
        float r[8];
        #pragma unroll
        for (int j = 0; j < 8; ++j) {
            const float v = b[j];
            r[j] = opaque(v * v);
        }
        for (int i = 8; i < 128; i += 8) {
            #pragma unroll
            for (int j = 0; j < 8; ++j) {
                const float v = b[i + j];
                r[j] += opaque(v * v);
            }
        }
        const float res = ((r[0] + r[1]) + (r[2] + r[3])) + ((r[4] + r[5]) + (r[6] + r[7]));
        total = (half == 0) ? res : (total + res);
    }
    return total;
}

// ---------------------------------------------------------------- kernel Sx
__global__ void sx_kernel(const float* __restrict__ x, float* __restrict__ sx) {
    const int row = blockIdx.x * blockDim.x + threadIdx.x;
    sx[row] = np_sumsq_256(x + (size_t)row * DIMD);
}

// ---------------------------------------------------------------- kernel Se
__global__ void se_kernel(const float* __restrict__ emb, float* __restrict__ se) {
    const int k = blockIdx.x * blockDim.x + threadIdx.x;
    se[k] = np_sumsq_256(emb + (size_t)k * DIMD);
}

// ---------------------------------------------------------------- conv emb->bf16
__global__ void conv_emb_kernel(const float* __restrict__ emb, unsigned short* __restrict__ embh) {
    const int i = blockIdx.x * blockDim.x + threadIdx.x;  // float4 index
    const float4 v = ((const float4*)emb)[i];
    ushort4 h;
    h.x = f2bf(v.x); h.y = f2bf(v.y); h.z = f2bf(v.z); h.w = f2bf(v.w);
    ((ushort4*)embh)[i] = h;
}

// ---------------------------------------------------------------- kernel P1
// Single-pass bf16 MFMA prune, v2:
//  - A panel (64 rows x 256 k) in REGISTERS per wave (no A LDS traffic)
//  - B staged via global_load_lds (16B) into a linear double buffer with
//    XOR swizzle applied on the pre-swizzled GLOBAL source + swizzled read
//    (both-sides rule): physical slot p of code row holds logical slot
//    p ^ (code&7); reader uses slot (ks*4+quad) ^ (lm&7) -> 2-way (free).
//  - per tile: 4-wave merged GLOBAL prefix max via LDS, then collect.
__global__ __launch_bounds__(256, 2)
void pass1_kernel(const float* __restrict__ x, const unsigned short* __restrict__ embh,
                  unsigned int* __restrict__ cand, int* __restrict__ cnt_out) {
    __shared__ unsigned short Bs[2][8192];   // 2 x 16 KB: 128 codes x 64 k, swizzled
    __shared__ float part[4][P1_BM];         // per-wave per-row tile max
    __shared__ float tilemax[P1_BM];         // merged tile max
    __shared__ int   cnts[P1_BM];

    const int t    = threadIdx.x;
    const int w    = t >> 6;
    const int lane = t & 63;
    const int quad = lane >> 4;
    const int lm   = lane & 15;
    const int row0 = blockIdx.x * P1_BM;

    if (t < P1_BM) cnts[t] = 0;

    // ---- A panel -> registers: afr[f][c] = bf16(x[row0+f*16+lm][c*32+quad*8 ..+7])
    bf16x8 afr[4][8];
    #pragma unroll
    for (int f = 0; f < 4; ++f) {
        const float* xr = x + (size_t)(row0 + f * 16 + lm) * DIMD + quad * 8;
        #pragma unroll
        for (int c = 0; c < 8; ++c) {
            const float4 v0 = *(const float4*)(xr + c * 32);
            const float4 v1 = *(const float4*)(xr + c * 32 + 4);
            bf16x8 h;
            h[0] = (short)f2bf(v0.x); h[1] = (short)f2bf(v0.y);
            h[2] = (short)f2bf(v0.z); h[3] = (short)f2bf(v0.w);
            h[4] = (short)f2bf(v1.x); h[5] = (short)f2bf(v1.y);
            h[6] = (short)f2bf(v1.z); h[7] = (short)f2bf(v1.w);
            afr[f][c] = h;
        }
    }

    // stage chunk m (c0=(m>>2)*128 codes, kcb=(m&3)*64 k) into Bs[buf]
    auto stage = [&](int buf, int m) {
        const int c0  = (m >> 2) * P1_BN;
        const int kcb = (m & 3) * 64;
        #pragma unroll
        for (int i = 0; i < 4; ++i) {
            const int seg  = i * 4 + w;                        // 0..15, wave-uniform
            const int code = seg * 8 + (lane >> 3);            // 0..127
            const int kk   = ((lane & 7) ^ ((lane >> 3) & 7)) * 8;  // pre-swizzled src
            const unsigned short* src = embh + (size_t)(c0 + code) * DIMD + kcb + kk;
            gload_lds16(src, &Bs[buf][seg * 512]);             // dest linear, 1 KB/issue
        }
    };

    stage(0, 0);
    asm volatile("s_waitcnt vmcnt(0)" ::: "memory");
    __syncthreads();

    float rmg[4][4];
    #pragma unroll
    for (int f = 0; f < 4; ++f)
        #pragma unroll
        for (int reg = 0; reg < 4; ++reg) rmg[f][reg] = -INFINITY;

    int buf = 0;
    for (int tile = 0; tile < NT; ++tile) {
        const int c0 = tile * P1_BN;
        f32x4 acc[4][2];
        #pragma unroll
        for (int f = 0; f < 4; ++f)
            #pragma unroll
            for (int g = 0; g < 2; ++g) acc[f][g] = (f32x4){0.f, 0.f, 0.f, 0.f};

        #pragma unroll
        for (int kb = 0; kb < 4; ++kb) {
            const int m = tile * 4 + kb;
            if (m < NT * 4 - 1) stage(buf ^ 1, m + 1);   // prefetch next chunk

            // compute chunk kb from Bs[buf] (K=64 = 2 MFMA K-steps)
            #pragma unroll
            for (int ks = 0; ks < 2; ++ks) {
                bf16x8 b[2];
                #pragma unroll
                for (int g = 0; g < 2; ++g) {
                    const int j = w * 32 + g * 16 + lm;
                    b[g] = *(const bf16x8*)
                        &Bs[buf][j * 64 + ((((ks << 2) + quad) ^ (lm & 7)) << 3)];
                }
                #pragma unroll
                for (int f = 0; f < 4; ++f)
                    #pragma unroll
                    for (int g = 0; g < 2; ++g)
                        acc[f][g] = __builtin_amdgcn_mfma_f32_16x16x32_bf16(
                            afr[f][kb * 2 + ks], b[g], acc[f][g], 0, 0, 0);
            }

            if (kb == 3) {
                // epilogue A: per-wave per-row max over this tile's 32 cols
                #pragma unroll
                for (int f = 0; f < 4; ++f) {
                    f32x4 mm4;
                    #pragma unroll
                    for (int reg = 0; reg < 4; ++reg) {
                        float mm = fmaxf(acc[f][0][reg], acc[f][1][reg]);
                        #pragma unroll
                        for (int off = 1; off < 16; off <<= 1)
                            mm = fmaxf(mm, __shfl_xor(mm, off, 64));  // within quad group
                        mm4[reg] = mm;
                    }
                    if (lm == 0)
                        *(f32x4*)&part[w][f * 16 + quad * 4] = mm4;
                }
            }

            asm volatile("s_waitcnt vmcnt(0)" ::: "memory");
            __syncthreads();
            buf ^= 1;
        }

        // merge 4 waves -> tile max (128 cols), then global prefix max
        if (t < P1_BM)
            tilemax[t] = fmaxf(fmaxf(part[0][t], part[1][t]),
                               fmaxf(part[2][t], part[3][t]));
        __syncthreads();

        // epilogue B: threshold vs global prefix max (tile-inclusive), collect
        #pragma unroll
        for (int f = 0; f < 4; ++f) {
            const f32x4 tm = *(const f32x4*)&tilemax[f * 16 + quad * 4];
            #pragma unroll
            for (int reg = 0; reg < 4; ++reg) {
                rmg[f][reg] = fmaxf(rmg[f][reg], tm[reg]);
                const float thr = rmg[f][reg] - TAU2;
                const int r = f * 16 + quad * 4 + reg;
                #pragma unroll
                for (int g = 0; g < 2; ++g) {
                    const float dv = acc[f][g][reg];
                    if (dv > thr) {
                        const int slot = atomicAdd(&cnts[r], 1);
                        if (slot < CAP) {
                            const unsigned int ub =
                                __builtin_bit_cast(unsigned int, fmaxf(dv, 0.0f));
                            cand[(size_t)(row0 + r) * CAP + slot] =
                                (ub & 0xFFFFF000u) |
                                (unsigned int)(c0 + w * 32 + g * 16 + lm);
                        }
                    }
                }
            }
        }
    }
    __syncthreads();
    if (t < P1_BM) cnt_out[row0 + t] = (cnts[t] > CAP) ? -1 : cnts[t];
}

// ---------------------------------------------------------------- kernel P2
// Re-filter stored candidates against the FINAL max dot (present among the
// stored keys), then exact np-semantics re-rank of survivors (~3.5/row):
// dist = fl(fl(sx - 2*dot) + se), dot = sequential fp32 FMA chain
// (validated R5/R6). x row staged to LDS once per wave; chain fully
// unrolled so e-loads pipeline deep. One wave per row.
__global__ __launch_bounds__(256, 4)
void pass2_kernel(const float* __restrict__ x, const float* __restrict__ emb,
                  const float* __restrict__ sx, const float* __restrict__ se,
                  const unsigned int* __restrict__ cand, const int* __restrict__ cnt,
                  int* __restrict__ out_idx) {
    __shared__ float4 xsh[4][64];
    const int w = threadIdx.x >> 6, lane = threadIdx.x & 63;
    const int row = blockIdx.x * 4 + w;
    const int n = cnt[row];
    const float sxr = sx[row];

    xsh[w][lane] = ((const float4*)(x + (size_t)row * DIMD))[lane];
    __syncthreads();
    const float4* xs4 = &xsh[w][0];

    float bestd = INFINITY;
    int   bestc = 0x7fffffff;

    if (n >= 1 && n <= CAP) {
        float dtil = -INFINITY;
        int   code = 0;
        if (lane < n) {
            const unsigned int word = cand[(size_t)row * CAP + lane];
            dtil = __builtin_bit_cast(float, word & 0xFFFFF000u);
            code = (int)(word & 0xFFFu);
        }
        // wave max of stored (truncated) dots == final max - O(2.5e-6)
        float mx = dtil;
        #pragma unroll
        for (int off = 1; off < 64; off <<= 1)
            mx = fmaxf(mx, __shfl_xor(mx, off, 64));
        const bool active = (lane < n) && (dtil > mx - TAU2B);
        if (active) {
            const float4* ep4 = (const float4*)(emb + (size_t)code * DIMD);
            float a = 0.0f;
            #pragma unroll
            for (int d4 = 0; d4 < DIMD / 4; ++d4) {
                const float4 ev = ep4[d4];
                const float4 xv = xs4[d4];
                a = fmaf(xv.x, ev.x, a);
                a = fmaf(xv.y, ev.y, a);
                a = fmaf(xv.z, ev.z, a);
                a = fmaf(xv.w, ev.w, a);
            }
            const float t1 = sxr - 2.0f * a;   // fl(sx - 2*dot)
            bestd = t1 + se[code];             // fl(t1 + se)
            bestc = code;
        }
    } else {
        // overflow / safety fallback: full exact scan (ascending per lane)
        for (int c = lane; c < KCODES; c += 64) {
            const float* ep = emb + (size_t)c * DIMD;
            float a = 0.0f;
            for (int d4 = 0; d4 < DIMD / 4; ++d4) {
                const float4 xv = xs4[d4];
                const float4 ev = ((const float4*)ep)[d4];
                a = fmaf(xv.x, ev.x, a);
                a = fmaf(xv.y, ev.y, a);
                a = fmaf(xv.z, ev.z, a);
                a = fmaf(xv.w, ev.w, a);
            }
            const float t1 = sxr - 2.0f * a;
            const float dd = t1 + se[c];
            if (dd < bestd || (dd == bestd && c < bestc)) { bestd = dd; bestc = c; }
        }
    }
    // wave argmin, lexicographic (value, code): np first-occurrence semantics
    #pragma unroll
    for (int off = 32; off > 0; off >>= 1) {
        const float od = __shfl_down(bestd, off, 64);
        const int   oc = __shfl_down(bestc, off, 64);
        if (od < bestd || (od == bestd && oc < bestc)) { bestd = od; bestc = oc; }
    }
    if (lane == 0) out_idx[row] = bestc;
}

// ---------------------------------------------------------------- kernel C
// gather emb[idx] -> quantized, write indices as float, per-block partial loss.
__global__ void gather_loss_kernel(const float* __restrict__ x, const float* __restrict__ emb,
                                   const int* __restrict__ idxs, float* __restrict__ out,
                                   float* __restrict__ partial) {
    const int w = threadIdx.x >> 6, lane = threadIdx.x & 63;
    const int row = blockIdx.x * 4 + w;
    const int idx = idxs[row];
    const float4 e4 = ((const float4*)(emb + (size_t)idx * DIMD))[lane];
    const float4 x4 = ((const float4*)(x + (size_t)row * DIMD))[lane];
    ((float4*)(out + (size_t)row * DIMD))[lane] = e4;
    const float dx = e4.x - x4.x, dy = e4.y - x4.y, dz = e4.z - x4.z, dw = e4.w - x4.w;
    float s = dx * dx + dy * dy + dz * dz + dw * dw;
    #pragma unroll
    for (int off = 32; off > 0; off >>= 1) s += __shfl_down(s, off, 64);
    __shared__ float wsum[4];
    if (lane == 0) wsum[w] = s;
    __syncthreads();
    if (threadIdx.x == 0)
        partial[blockIdx.x] = wsum[0] + wsum[1] + wsum[2] + wsum[3];
    if (lane == 0) out[QN + 1 + row] = (float)idx;
}

// ---------------------------------------------------------------- kernel L
// reduce 16384 per-block partials -> loss (LDS tree, double accum)
__global__ void loss_reduce_kernel(const float* __restrict__ partial, float* __restrict__ out) {
    const int t = threadIdx.x;           // 256 threads, 1 block
    double s = 0.0;
    for (int i = t; i < NROWS / 4; i += 256) s += (double)partial[i];
    __shared__ double tsum[256];
    tsum[t] = s;
    __syncthreads();
    #pragma unroll
    for (int off = 128; off > 0; off >>= 1) {
        if (t < off) tsum[t] += tsum[t + off];
        __syncthreads();
    }
    if (t == 0) out[QN] = (float)(tsum[0] * (1.25 / (double)QN));
}

// ---------------------------------------------------------------- launcher
extern "C" void kernel_launch(void* const* d_in, const int* in_sizes, int n_in,
                              void* d_out, int out_size, void* d_ws, size_t ws_size,
                              hipStream_t stream) {
    const float* x   = (const float*)d_in[0];   // [65536, 256]
    const float* emb = (const float*)d_in[1];   // [4096, 256]
    float* out = (float*)d_out;                 // q[16777216] | loss[1] | idx[65536]

    char* ws = (char*)d_ws;
    unsigned short* embh = (unsigned short*)ws;           ws += (size_t)KCODES * DIMD * 2; // 2 MB
    float* sx  = (float*)ws;                              ws += (size_t)NROWS * 4;         // 256 KB
    float* se  = (float*)ws;                              ws += (size_t)KCODES * 4;        // 16 KB
    unsigned int* cand = (unsigned int*)ws;               ws += (size_t)NROWS * CAP * 4;   // 12.6 MB
    int*   cnt  = (int*)ws;                               ws += (size_t)NROWS * 4;         // 256 KB
    int*   idx  = (int*)ws;                               ws += (size_t)NROWS * 4;         // 256 KB
    float* partial = (float*)ws;                                                           // 64 KB

    conv_emb_kernel<<<KCODES * DIMD / 4 / 256, 256, 0, stream>>>(emb, embh);
    sx_kernel<<<NROWS / 256, 256, 0, stream>>>(x, sx);
    se_kernel<<<KCODES / 256, 256, 0, stream>>>(emb, se);
    pass1_kernel<<<NROWS / P1_BM, 256, 0, stream>>>(x, embh, cand, cnt);
    pass2_kernel<<<NROWS / 4, 256, 0, stream>>>(x, emb, sx, se, cand, cnt, idx);
    gather_loss_kernel<<<NROWS / 4, 256, 0, stream>>>(x, emb, idx, out, partial);
    loss_reduce_kernel<<<1, 256, 0, stream>>>(partial, out);
}

// Round 5
// 793.297 us; speedup vs baseline: 1.5354x; 1.3240x over previous
//
#include <hip/hip_runtime.h>
#include <math.h>

// Problem constants (fixed by reference)
#define DIMD 256
#define KCODES 4096
#define NROWS 65536
#define QN (NROWS * DIMD)   // 16777216 quantized elements

// ---------------- pass1 (bf16 MFMA prune) parameters ----------------
constexpr int P1_BM = 64;      // rows per block
constexpr int P1_BN = 128;     // codes per N-tile
constexpr int NT    = KCODES / P1_BN;   // 32 N-tiles
// Dot-scale margin: candidate iff dot > running_global_prefix_max - TAU2.
// Error stack (dot scale): bf16 operand rounding <=2.3e-4 (worst), np fp32
// quantization ~3e-5, dropped se <=0.8e-5  ->  TAU2 = 7.5e-4 is ~2.8x margin.
// Prefix max (tile-inclusive, merged across all 4 waves) <= final max at
// every collection point -> collected set is a SUPERSET of the final-max
// candidate set (E ~ 7/row). Stored word packs the MFMA dot (top-20 fp32
// bits) with the 12-bit code so pass2 recovers the FINAL max and re-filters
// to ~3.5/row before the exact re-rank. Key truncation < 2.5e-6 covered by
// the +1e-5 pass2 margin.
constexpr float TAU2 = 7.5e-4f;
constexpr float TAU2B = TAU2 + 1e-5f;   // pass2 re-filter margin (key truncation)
constexpr int CAP   = 48;      // candidate slots per row (overflow -> exact fallback)
constexpr int NS    = 8;       // pass2 LDS staging slots (survivors E~3.5)

typedef __attribute__((ext_vector_type(8))) short bf16x8;
typedef __attribute__((ext_vector_type(4))) float f32x4;

// RNE float -> bf16 bits (inputs finite; no NaN handling needed)
__device__ __forceinline__ unsigned short f2bf(float f) {
    unsigned int u = __builtin_bit_cast(unsigned int, f);
    u += 0x7fffu + ((u >> 16) & 1u);
    return (unsigned short)(u >> 16);
}

// Opaque barrier: forces v to be a rounded fp32 value (blocks FMA contraction)
__device__ __forceinline__ float opaque(float v) {
    asm volatile("" : "+v"(v));
    return v;
}

// async global->LDS, 16 B per lane, dest = wave-uniform base + lane*16
__device__ __forceinline__ void gload_lds16(const void* g, void* l) {
    __builtin_amdgcn_global_load_lds(
        (const __attribute__((address_space(1))) unsigned int*)g,
        (__attribute__((address_space(3))) unsigned int*)l, 16, 0, 0);
}

// numpy pairwise_sum of 256 fp32 squares, bit-exact replication (validated R4)
__device__ __forceinline__ float np_sumsq_256(const float* __restrict__ p) {
    float total = 0.0f;
    #pragma unroll
    for (int half = 0; half < 2; ++half) {
        const float* b = p + half * 128;
        float r[8];
        #pragma unroll
        for (int j = 0; j < 8; ++j) {
            const float v = b[j];
            r[j] = opaque(v * v);
        }
        for (int i = 8; i < 128; i += 8) {
            #pragma unroll
            for (int j = 0; j < 8; ++j) {
                const float v = b[i + j];
                r[j] += opaque(v * v);
            }
        }
        const float res = ((r[0] + r[1]) + (r[2] + r[3])) + ((r[4] + r[5]) + (r[6] + r[7]));
        total = (half == 0) ? res : (total + res);
    }
    return total;
}

// ---------------------------------------------------------------- kernel Sx
__global__ void sx_kernel(const float* __restrict__ x, float* __restrict__ sx) {
    const int row = blockIdx.x * blockDim.x + threadIdx.x;
    sx[row] = np_sumsq_256(x + (size_t)row * DIMD);
}

// ---------------------------------------------------------------- kernel Se
__global__ void se_kernel(const float* __restrict__ emb, float* __restrict__ se) {
    const int k = blockIdx.x * blockDim.x + threadIdx.x;
    se[k] = np_sumsq_256(emb + (size_t)k * DIMD);
}

// ---------------------------------------------------------------- conv emb->bf16
__global__ void conv_emb_kernel(const float* __restrict__ emb, unsigned short* __restrict__ embh) {
    const int i = blockIdx.x * blockDim.x + threadIdx.x;  // float4 index
    const float4 v = ((const float4*)emb)[i];
    ushort4 h;
    h.x = f2bf(v.x); h.y = f2bf(v.y); h.z = f2bf(v.z); h.w = f2bf(v.w);
    ((ushort4*)embh)[i] = h;
}

// ---------------------------------------------------------------- kernel P1
// Single-pass bf16 MFMA prune, v3 (spill-free):
//  - waves tiled 2x2: wave (wr,wc) owns 32 rows x 64 cols.
//    A panel per wave = afr[2][8] = 64 VGPRs (v2's afr[4][8]=128 spilled).
//  - B staged via global_load_lds (16B) into a linear double buffer with
//    XOR swizzle on the pre-swizzled GLOBAL source + swizzled read
//    (both-sides rule, validated R4): phys slot p of code row c holds
//    logical slot p ^ (c&7); reader uses (ks*4+quad) ^ (lm&7).
//  - per tile: 4-wave merged GLOBAL prefix max via LDS, then collect.
__global__ __launch_bounds__(256, 2)
void pass1_kernel(const float* __restrict__ x, const unsigned short* __restrict__ embh,
                  unsigned int* __restrict__ cand, int* __restrict__ cnt_out) {
    __shared__ unsigned short Bs[2][8192];   // 2 x 16 KB: 128 codes x 64 k, swizzled
    __shared__ float part[4][32];            // per-wave per-row tile max (32 rows each)
    __shared__ float tilemax[P1_BM];         // merged tile max
    __shared__ int   cnts[P1_BM];

    const int t    = threadIdx.x;
    const int w    = t >> 6;
    const int lane = t & 63;
    const int quad = lane >> 4;
    const int lm   = lane & 15;
    const int wr   = w >> 1;           // row half: rows wr*32 .. +31
    const int wc   = w & 1;            // col half: cols wc*64 .. +63
    const int row0 = blockIdx.x * P1_BM;

    if (t < P1_BM) cnts[t] = 0;

    // ---- A panel -> registers: afr[f][c] = bf16(x[row0+wr*32+f*16+lm][c*32+quad*8 ..+7])
    bf16x8 afr[2][8];
    #pragma unroll
    for (int f = 0; f < 2; ++f) {
        const float* xr = x + (size_t)(row0 + wr * 32 + f * 16 + lm) * DIMD + quad * 8;
        #pragma unroll
        for (int c = 0; c < 8; ++c) {
            const float4 v0 = *(const float4*)(xr + c * 32);
            const float4 v1 = *(const float4*)(xr + c * 32 + 4);
            bf16x8 h;
            h[0] = (short)f2bf(v0.x); h[1] = (short)f2bf(v0.y);
            h[2] = (short)f2bf(v0.z); h[3] = (short)f2bf(v0.w);
            h[4] = (short)f2bf(v1.x); h[5] = (short)f2bf(v1.y);
            h[6] = (short)f2bf(v1.z); h[7] = (short)f2bf(v1.w);
            afr[f][c] = h;
        }
    }

    // stage chunk m (c0=(m>>2)*128 codes, kcb=(m&3)*64 k) into Bs[buf]
    auto stage = [&](int buf, int m) {
        const int c0  = (m >> 2) * P1_BN;
        const int kcb = (m & 3) * 64;
        #pragma unroll
        for (int i = 0; i < 4; ++i) {
            const int seg  = i * 4 + w;                        // 0..15, wave-uniform
            const int code = seg * 8 + (lane >> 3);            // 0..127
            const int kk   = ((lane & 7) ^ ((lane >> 3) & 7)) * 8;  // pre-swizzled src
            const unsigned short* src = embh + (size_t)(c0 + code) * DIMD + kcb + kk;
            gload_lds16(src, &Bs[buf][seg * 512]);             // dest linear, 1 KB/issue
        }
    };

    stage(0, 0);
    asm volatile("s_waitcnt vmcnt(0)" ::: "memory");
    __syncthreads();

    float rmg[2][4];
    #pragma unroll
    for (int f = 0; f < 2; ++f)
        #pragma unroll
        for (int reg = 0; reg < 4; ++reg) rmg[f][reg] = -INFINITY;

    int buf = 0;
    for (int tile = 0; tile < NT; ++tile) {
        const int c0 = tile * P1_BN;
        f32x4 acc[2][4];
        #pragma unroll
        for (int f = 0; f < 2; ++f)
            #pragma unroll
            for (int g = 0; g < 4; ++g) acc[f][g] = (f32x4){0.f, 0.f, 0.f, 0.f};

        #pragma unroll
        for (int kb = 0; kb < 4; ++kb) {
            const int m = tile * 4 + kb;
            if (m < NT * 4 - 1) stage(buf ^ 1, m + 1);   // prefetch next chunk

            // compute chunk kb from Bs[buf] (K=64 = 2 MFMA K-steps)
            #pragma unroll
            for (int ks = 0; ks < 2; ++ks) {
                bf16x8 b[4];
                #pragma unroll
                for (int g = 0; g < 4; ++g) {
                    const int j = wc * 64 + g * 16 + lm;     // j&7 == lm&7
                    b[g] = *(const bf16x8*)
                        &Bs[buf][j * 64 + ((((ks << 2) + quad) ^ (lm & 7)) << 3)];
                }
                #pragma unroll
                for (int f = 0; f < 2; ++f)
                    #pragma unroll
                    for (int g = 0; g < 4; ++g)
                        acc[f][g] = __builtin_amdgcn_mfma_f32_16x16x32_bf16(
                            afr[f][kb * 2 + ks], b[g], acc[f][g], 0, 0, 0);
            }

            if (kb == 3) {
                // epilogue A: per-wave per-row max over this tile's 64 cols
                #pragma unroll
                for (int f = 0; f < 2; ++f) {
                    f32x4 mm4;
                    #pragma unroll
                    for (int reg = 0; reg < 4; ++reg) {
                        float mm = fmaxf(fmaxf(acc[f][0][reg], acc[f][1][reg]),
                                         fmaxf(acc[f][2][reg], acc[f][3][reg]));
                        #pragma unroll
                        for (int off = 1; off < 16; off <<= 1)
                            mm = fmaxf(mm, __shfl_xor(mm, off, 64));  // within quad group
                        mm4[reg] = mm;
                    }
                    if (lm == 0)
                        *(f32x4*)&part[w][f * 16 + quad * 4] = mm4;
                }
            }

            asm volatile("s_waitcnt vmcnt(0)" ::: "memory");
            __syncthreads();
            buf ^= 1;
        }

        // merge 2 col-waves per row-half -> tile max (64 rows), then prefix max
        if (t < P1_BM) {
            const int trh = t >> 5, loc = t & 31;
            tilemax[t] = fmaxf(part[trh * 2][loc], part[trh * 2 + 1][loc]);
        }
        __syncthreads();

        // epilogue B: threshold vs global prefix max (tile-inclusive), collect
        #pragma unroll
        for (int f = 0; f < 2; ++f) {
            const f32x4 tm = *(const f32x4*)&tilemax[wr * 32 + f * 16 + quad * 4];
            #pragma unroll
            for (int reg = 0; reg < 4; ++reg) {
                rmg[f][reg] = fmaxf(rmg[f][reg], tm[reg]);
                const float thr = rmg[f][reg] - TAU2;
                const int r = wr * 32 + f * 16 + quad * 4 + reg;
                #pragma unroll
                for (int g = 0; g < 4; ++g) {
                    const float dv = acc[f][g][reg];
                    if (dv > thr) {
                        const int slot = atomicAdd(&cnts[r], 1);
                        if (slot < CAP) {
                            const unsigned int ub =
                                __builtin_bit_cast(unsigned int, fmaxf(dv, 0.0f));
                            cand[(size_t)(row0 + r) * CAP + slot] =
                                (ub & 0xFFFFF000u) |
                                (unsigned int)(c0 + wc * 64 + g * 16 + lm);
                        }
                    }
                }
            }
        }
    }
    __syncthreads();
    if (t < P1_BM) cnt_out[row0 + t] = (cnts[t] > CAP) ? -1 : cnts[t];
}

// ---------------------------------------------------------------- kernel P2 (fused)
// Re-filter stored candidates against the FINAL max dot (present among the
// stored keys), cooperatively stage surviving emb rows into LDS (one
// coalesced 1KB load per candidate -> one latency round, not 64), then run
// the exact np-semantics re-rank from LDS: dist = fl(fl(sx-2*dot)+se),
// dot = sequential fp32 FMA chain (validated R5/R6). Finally gather the
// winning emb row, write quantized output + idx + per-row loss partial
// (gather_loss_kernel fused away). One wave per row.
__global__ __launch_bounds__(256, 2)
void pass2_kernel(const float* __restrict__ x, const float* __restrict__ emb,
                  const float* __restrict__ sx, const float* __restrict__ se,
                  const unsigned int* __restrict__ cand, const int* __restrict__ cnt,
                  float* __restrict__ out, float* __restrict__ partial) {
    __shared__ float4 xsh[4][64];
    __shared__ float4 esh[4][NS][65];     // +1 float4 pad: slot-strided reads conflict-free
    const int w = threadIdx.x >> 6, lane = threadIdx.x & 63;
    const int row = blockIdx.x * 4 + w;
    const int n = cnt[row];
    const float sxr = sx[row];
    const float4* emb4 = (const float4*)emb;

    const float4 myx = ((const float4*)(x + (size_t)row * DIMD))[lane];
    xsh[w][lane] = myx;
    const float4* xs4 = &xsh[w][0];

    float bestd = INFINITY;
    int   bestc = 0x7fffffff;

    if (n >= 1 && n <= CAP) {
        float dtil = -INFINITY;
        int   code = 0;
        if (lane < n) {
            const unsigned int word = cand[(size_t)row * CAP + lane];
            dtil = __builtin_bit_cast(float, word & 0xFFFFF000u);
            code = (int)(word & 0xFFFu);
        }
        // wave max of stored (truncated) dots == final max - O(2.5e-6)
        float mx = dtil;
        #pragma unroll
        for (int off = 1; off < 64; off <<= 1)
            mx = fmaxf(mx, __shfl_xor(mx, off, 64));
        const bool active = (lane < n) && (dtil > mx - TAU2B);
        const unsigned long long mask = __ballot(active);
        const int nact = __popcll(mask);
        const int slot = __popcll(mask & ((1ull << lane) - 1ull));
        // cooperatively stage up to NS surviving rows into LDS
        unsigned long long mm = mask;
        const int ns = nact < NS ? nact : NS;
        for (int i = 0; i < ns; ++i) {
            const int li = __ffsll((unsigned long long)mm) - 1;
            mm &= mm - 1;
            const int bc = __shfl(code, li, 64);
            esh[w][i][lane] = emb4[(size_t)bc * 64 + lane];
        }
        if (active) {
            float a = 0.0f;
            if (slot < NS) {
                const float4* ep4 = &esh[w][slot][0];
                #pragma unroll
                for (int d4 = 0; d4 < DIMD / 4; ++d4) {
                    const float4 ev = ep4[d4];
                    const float4 xv = xs4[d4];
                    a = fmaf(xv.x, ev.x, a);
                    a = fmaf(xv.y, ev.y, a);
                    a = fmaf(xv.z, ev.z, a);
                    a = fmaf(xv.w, ev.w, a);
                }
            } else {  // rare: >NS survivors, read from global
                const float4* ep4 = (const float4*)(emb + (size_t)code * DIMD);
                #pragma unroll
                for (int d4 = 0; d4 < DIMD / 4; ++d4) {
                    const float4 ev = ep4[d4];
                    const float4 xv = xs4[d4];
                    a = fmaf(xv.x, ev.x, a);
                    a = fmaf(xv.y, ev.y, a);
                    a = fmaf(xv.z, ev.z, a);
                    a = fmaf(xv.w, ev.w, a);
                }
            }
            const float t1 = sxr - 2.0f * a;   // fl(sx - 2*dot)
            bestd = t1 + se[code];             // fl(t1 + se)
            bestc = code;
        }
    } else {
        // overflow / safety fallback: full exact scan (ascending per lane)
        for (int c = lane; c < KCODES; c += 64) {
            const float* ep = emb + (size_t)c * DIMD;
            float a = 0.0f;
            for (int d4 = 0; d4 < DIMD / 4; ++d4) {
                const float4 xv = xs4[d4];
                const float4 ev = ((const float4*)ep)[d4];
                a = fmaf(xv.x, ev.x, a);
                a = fmaf(xv.y, ev.y, a);
                a = fmaf(xv.z, ev.z, a);
                a = fmaf(xv.w, ev.w, a);
            }
            const float t1 = sxr - 2.0f * a;
            const float dd = t1 + se[c];
            if (dd < bestd || (dd == bestd && c < bestc)) { bestd = dd; bestc = c; }
        }
    }
    // wave argmin, lexicographic (value, code): np first-occurrence semantics
    #pragma unroll
    for (int off = 32; off > 0; off >>= 1) {
        const float od = __shfl_down(bestd, off, 64);
        const int   oc = __shfl_down(bestc, off, 64);
        if (od < bestd || (od == bestd && oc < bestc)) { bestd = od; bestc = oc; }
    }
    bestc = __shfl(bestc, 0, 64);   // broadcast winner

    // fused epilogue: quantized row, idx, per-row loss partial
    const float4 e4 = emb4[(size_t)bestc * 64 + lane];
    ((float4*)(out + (size_t)row * DIMD))[lane] = e4;
    const float dx = e4.x - myx.x, dy = e4.y - myx.y,
                dz = e4.z - myx.z, dw = e4.w - myx.w;
    float s = dx * dx + dy * dy + dz * dz + dw * dw;
    #pragma unroll
    for (int off = 32; off > 0; off >>= 1) s += __shfl_down(s, off, 64);
    if (lane == 0) {
        partial[row] = s;
        out[QN + 1 + row] = (float)bestc;
    }
}

// ---------------------------------------------------------------- kernel L
// reduce 65536 per-row fp32 partials -> loss (LDS tree, double accum)
__global__ void loss_reduce_kernel(const float* __restrict__ partial, float* __restrict__ out) {
    const int t = threadIdx.x;           // 256 threads, 1 block
    double s = 0.0;
    for (int i = t; i < NROWS; i += 256) s += (double)partial[i];
    __shared__ double tsum[256];
    tsum[t] = s;
    __syncthreads();
    #pragma unroll
    for (int off = 128; off > 0; off >>= 1) {
        if (t < off) tsum[t] += tsum[t + off];
        __syncthreads();
    }
    if (t == 0) out[QN] = (float)(tsum[0] * (1.25 / (double)QN));
}

// ---------------------------------------------------------------- launcher
extern "C" void kernel_launch(void* const* d_in, const int* in_sizes, int n_in,
                              void* d_out, int out_size, void* d_ws, size_t ws_size,
                              hipStream_t stream) {
    const float* x   = (const float*)d_in[0];   // [65536, 256]
    const float* emb = (const float*)d_in[1];   // [4096, 256]
    float* out = (float*)d_out;                 // q[16777216] | loss[1] | idx[65536]

    char* ws = (char*)d_ws;
    unsigned short* embh = (unsigned short*)ws;           ws += (size_t)KCODES * DIMD * 2; // 2 MB
    float* sx  = (float*)ws;                              ws += (size_t)NROWS * 4;         // 256 KB
    float* se  = (float*)ws;                              ws += (size_t)KCODES * 4;        // 16 KB
    unsigned int* cand = (unsigned int*)ws;               ws += (size_t)NROWS * CAP * 4;   // 12.6 MB
    int*   cnt  = (int*)ws;                               ws += (size_t)NROWS * 4;         // 256 KB
    float* partial = (float*)ws;                                                           // 256 KB

    conv_emb_kernel<<<KCODES * DIMD / 4 / 256, 256, 0, stream>>>(emb, embh);
    sx_kernel<<<NROWS / 256, 256, 0, stream>>>(x, sx);
    se_kernel<<<KCODES / 256, 256, 0, stream>>>(emb, se);
    pass1_kernel<<<NROWS / P1_BM, 256, 0, stream>>>(x, embh, cand, cnt);
    pass2_kernel<<<NROWS / 4, 256, 0, stream>>>(x, emb, sx, se, cand, cnt, out, partial);
    loss_reduce_kernel<<<1, 256, 0, stream>>>(partial, out);
}

// Round 6
// 782.366 us; speedup vs baseline: 1.5569x; 1.0140x over previous
//
#include <hip/hip_runtime.h>
#include <math.h>

// Problem constants (fixed by reference)
#define DIMD 256
#define KCODES 4096
#define NROWS 65536
#define QN (NROWS * DIMD)   // 16777216 quantized elements

// ---------------- pass1 (bf16 MFMA prune) parameters ----------------
constexpr int P1_BM = 64;      // rows per block
constexpr int P1_BN = 128;     // codes per N-tile
constexpr int NT    = KCODES / P1_BN;   // 32 N-tiles
// Dot-scale margin: candidate iff dot > running_global_prefix_max - TAU2.
// Error stack (dot scale): bf16 operand rounding <=2.3e-4 (worst), np fp32
// quantization ~3e-5, dropped se <=0.8e-5  ->  TAU2 = 7.5e-4 is ~2.8x margin.
// Prefix max <= final max at every collection point -> superset of the
// final-max candidate set (E ~ 7/row). Stored word packs the MFMA dot
// (top-20 fp32 bits) + 12-bit code; pass2 recovers the FINAL max and
// re-filters to ~3.5/row before the exact re-rank. Key truncation < 2.5e-6
// covered by the +1e-5 pass2 margin.
constexpr float TAU2 = 7.5e-4f;
constexpr float TAU2B = TAU2 + 1e-5f;   // pass2 re-filter margin (key truncation)
constexpr int CAP   = 48;      // candidate slots per row (overflow -> exact fallback)
constexpr int NS    = 8;       // pass2 LDS staging slots (survivors E~3.5)

typedef __attribute__((ext_vector_type(8))) short bf16x8;
typedef __attribute__((ext_vector_type(4))) float f32x4;

#define VM8() asm volatile("s_waitcnt vmcnt(8)" ::: "memory")
#define VM4() asm volatile("s_waitcnt vmcnt(4)" ::: "memory")
#define VM0() asm volatile("s_waitcnt vmcnt(0)" ::: "memory")

// RNE float -> bf16 bits (inputs finite; no NaN handling needed)
__device__ __forceinline__ unsigned short f2bf(float f) {
    unsigned int u = __builtin_bit_cast(unsigned int, f);
    u += 0x7fffu + ((u >> 16) & 1u);
    return (unsigned short)(u >> 16);
}

// Opaque barrier: forces v to be a rounded fp32 value (blocks FMA contraction)
__device__ __forceinline__ float opaque(float v) {
    asm volatile("" : "+v"(v));
    return v;
}

// async global->LDS, 16 B per lane, dest = wave-uniform base + lane*16
__device__ __forceinline__ void gload_lds16(const void* g, void* l) {
    __builtin_amdgcn_global_load_lds(
        (const __attribute__((address_space(1))) unsigned int*)g,
        (__attribute__((address_space(3))) unsigned int*)l, 16, 0, 0);
}

// ---------------------------------------------------------------- kernel Sx
// 8 lanes per row; lane j owns np accumulator r[j]. Bit-exact replication of
// the validated serial np pairwise_sum: r[j] chains are identical FP op
// sequences; the combine tree ((r0+r1)+(r2+r3))+((r4+r5)+(r6+r7)) is done
// with shfl_xor 1/2/4 (IEEE add commutative -> bit-identical on every lane).
__global__ void sx_kernel(const float* __restrict__ x, float* __restrict__ sx) {
    const int j   = threadIdx.x & 7;
    const int row = blockIdx.x * 32 + (threadIdx.x >> 3);
    const float* p = x + (size_t)row * DIMD;
    float total = 0.0f;
    #pragma unroll
    for (int half = 0; half < 2; ++half) {
        const float* b = p + half * 128;
        const float v0 = b[j];
        float r = opaque(v0 * v0);
        #pragma unroll
        for (int i = 8; i < 128; i += 8) {
            const float v = b[i + j];
            r += opaque(v * v);
        }
        const float s1  = r  + __shfl_xor(r, 1, 64);
        const float s2  = s1 + __shfl_xor(s1, 2, 64);
        const float res = s2 + __shfl_xor(s2, 4, 64);
        total = (half == 0) ? res : (total + res);
    }
    if (j == 0) sx[row] = total;
}

// ---------------------------------------------------------------- kernel Se
__global__ void se_kernel(const float* __restrict__ emb, float* __restrict__ se) {
    const int j   = threadIdx.x & 7;
    const int row = blockIdx.x * 32 + (threadIdx.x >> 3);
    const float* p = emb + (size_t)row * DIMD;
    float total = 0.0f;
    #pragma unroll
    for (int half = 0; half < 2; ++half) {
        const float* b = p + half * 128;
        const float v0 = b[j];
        float r = opaque(v0 * v0);
        #pragma unroll
        for (int i = 8; i < 128; i += 8) {
            const float v = b[i + j];
            r += opaque(v * v);
        }
        const float s1  = r  + __shfl_xor(r, 1, 64);
        const float s2  = s1 + __shfl_xor(s1, 2, 64);
        const float res = s2 + __shfl_xor(s2, 4, 64);
        total = (half == 0) ? res : (total + res);
    }
    if (j == 0) se[row] = total;
}

// ---------------------------------------------------------------- conv emb->bf16
__global__ void conv_emb_kernel(const float* __restrict__ emb, unsigned short* __restrict__ embh) {
    const int i = blockIdx.x * blockDim.x + threadIdx.x;  // float4 index
    const float4 v = ((const float4*)emb)[i];
    ushort4 h;
    h.x = f2bf(v.x); h.y = f2bf(v.y); h.z = f2bf(v.z); h.w = f2bf(v.w);
    ((ushort4*)embh)[i] = h;
}

// ---------------------------------------------------------------- kernel P1
// Single-pass bf16 MFMA prune, v4 (counted-vmcnt triple-buffer):
//  - waves tiled 2x2 (spill-free, validated R5): wave (wr,wc) = 32 rows x 64 cols,
//    A panel afr[2][8] = 64 VGPRs.
//  - B staged via global_load_lds (16B) into a TRIPLE buffer, prefetch depth 2,
//    counted vmcnt(8) per chunk (4 loads/stage/wave, 2 stages in flight) --
//    no per-chunk vmcnt(0) drain. One vmcnt(0) per tile after the epilogue's
//    global stores keeps the static counts valid (stores share vmcnt).
//  - XOR swizzle on pre-swizzled GLOBAL source + swizzled read (validated R5):
//    phys slot p of code row c holds logical slot p ^ (c&7);
//    reader uses (ks*4+quad) ^ (lm&7).
__global__ __launch_bounds__(256, 2)
void pass1_kernel(const float* __restrict__ x, const unsigned short* __restrict__ embh,
                  unsigned int* __restrict__ cand, int* __restrict__ cnt_out) {
    __shared__ unsigned short Bs[3][8192];   // 3 x 16 KB: 128 codes x 64 k, swizzled
    __shared__ float part[4][32];            // per-wave per-row tile max (32 rows each)
    __shared__ float tilemax[P1_BM];         // merged tile max
    __shared__ int   cnts[P1_BM];

    const int t    = threadIdx.x;
    const int w    = t >> 6;
    const int lane = t & 63;
    const int quad = lane >> 4;
    const int lm   = lane & 15;
    const int wr   = w >> 1;           // row half: rows wr*32 .. +31
    const int wc   = w & 1;            // col half: cols wc*64 .. +63
    const int row0 = blockIdx.x * P1_BM;

    if (t < P1_BM) cnts[t] = 0;

    // ---- A panel -> registers: afr[f][c] = bf16(x[row0+wr*32+f*16+lm][c*32+quad*8 ..+7])
    bf16x8 afr[2][8];
    #pragma unroll
    for (int f = 0; f < 2; ++f) {
        const float* xr = x + (size_t)(row0 + wr * 32 + f * 16 + lm) * DIMD + quad * 8;
        #pragma unroll
        for (int c = 0; c < 8; ++c) {
            const float4 v0 = *(const float4*)(xr + c * 32);
            const float4 v1 = *(const float4*)(xr + c * 32 + 4);
            bf16x8 h;
            h[0] = (short)f2bf(v0.x); h[1] = (short)f2bf(v0.y);
            h[2] = (short)f2bf(v0.z); h[3] = (short)f2bf(v0.w);
            h[4] = (short)f2bf(v1.x); h[5] = (short)f2bf(v1.y);
            h[6] = (short)f2bf(v1.z); h[7] = (short)f2bf(v1.w);
            afr[f][c] = h;
        }
    }

    // stage chunk m (c0=(m>>2)*128 codes, kcb=(m&3)*64 k) into Bs[buf]
    auto stage = [&](int buf, int m) {
        const int c0  = (m >> 2) * P1_BN;
        const int kcb = (m & 3) * 64;
        #pragma unroll
        for (int i = 0; i < 4; ++i) {
            const int seg  = i * 4 + w;                        // 0..15, wave-uniform
            const int code = seg * 8 + (lane >> 3);            // 0..127
            const int kk   = ((lane & 7) ^ ((lane >> 3) & 7)) * 8;  // pre-swizzled src
            const unsigned short* src = embh + (size_t)(c0 + code) * DIMD + kcb + kk;
            gload_lds16(src, &Bs[buf][seg * 512]);             // dest linear, 1 KB/issue
        }
    };

    stage(0, 0);
    stage(1, 1);
    int bc = 0;    // buffer holding the chunk we compute next

    float rmg[2][4];
    #pragma unroll
    for (int f = 0; f < 2; ++f)
        #pragma unroll
        for (int reg = 0; reg < 4; ++reg) rmg[f][reg] = -INFINITY;

    for (int tile = 0; tile < NT; ++tile) {
        const int c0 = tile * P1_BN;
        f32x4 acc[2][4];
        #pragma unroll
        for (int f = 0; f < 2; ++f)
            #pragma unroll
            for (int g = 0; g < 4; ++g) acc[f][g] = (f32x4){0.f, 0.f, 0.f, 0.f};

        #pragma unroll
        for (int kb = 0; kb < 4; ++kb) {
            const int m = tile * 4 + kb;
            __syncthreads();               // all waves done reading buf (m+2)%3 at m-1
            int st = bc + 2; if (st >= 3) st -= 3;
            if (tile < NT - 1) {
                stage(st, m + 2);
                VM8();                     // my chunk-m loads (2 stages newer in flight)
            } else {
                if (kb == 0) { stage(st, m + 2); VM8(); }
                else if (kb == 1) { stage(st, m + 2); VM8(); }
                else if (kb == 2) { VM4(); }
                else { VM0(); }
            }
            __syncthreads();               // all waves' chunk-m data in LDS

            // compute chunk m from Bs[bc] (K=64 = 2 MFMA K-steps)
            #pragma unroll
            for (int ks = 0; ks < 2; ++ks) {
                bf16x8 b[4];
                #pragma unroll
                for (int g = 0; g < 4; ++g) {
                    const int j = wc * 64 + g * 16 + lm;     // j&7 == lm&7
                    b[g] = *(const bf16x8*)
                        &Bs[bc][j * 64 + ((((ks << 2) + quad) ^ (lm & 7)) << 3)];
                }
                #pragma unroll
                for (int f = 0; f < 2; ++f)
                    #pragma unroll
                    for (int g = 0; g < 4; ++g)
                        acc[f][g] = __builtin_amdgcn_mfma_f32_16x16x32_bf16(
                            afr[f][kb * 2 + ks], b[g], acc[f][g], 0, 0, 0);
            }

            if (kb == 3) {
                // epilogue A: per-wave per-row max over this tile's 64 cols
                #pragma unroll
                for (int f = 0; f < 2; ++f) {
                    f32x4 mm4;
                    #pragma unroll
                    for (int reg = 0; reg < 4; ++reg) {
                        float mm = fmaxf(fmaxf(acc[f][0][reg], acc[f][1][reg]),
                                         fmaxf(acc[f][2][reg], acc[f][3][reg]));
                        #pragma unroll
                        for (int off = 1; off < 16; off <<= 1)
                            mm = fmaxf(mm, __shfl_xor(mm, off, 64));  // within quad group
                        mm4[reg] = mm;
                    }
                    if (lm == 0)
                        *(f32x4*)&part[w][f * 16 + quad * 4] = mm4;
                }
            }
            bc = (bc == 2) ? 0 : bc + 1;
        }

        // merge 2 col-waves per row-half -> tile max (64 rows), then prefix max
        __syncthreads();
        if (t < P1_BM) {
            const int trh = t >> 5, loc = t & 31;
            tilemax[t] = fmaxf(part[trh * 2][loc], part[trh * 2 + 1][loc]);
        }
        __syncthreads();

        // epilogue B: threshold vs global prefix max (tile-inclusive), collect
        #pragma unroll
        for (int f = 0; f < 2; ++f) {
            const f32x4 tm = *(const f32x4*)&tilemax[wr * 32 + f * 16 + quad * 4];
            #pragma unroll
            for (int reg = 0; reg < 4; ++reg) {
                rmg[f][reg] = fmaxf(rmg[f][reg], tm[reg]);
                const float thr = rmg[f][reg] - TAU2;
                const int r = wr * 32 + f * 16 + quad * 4 + reg;
                #pragma unroll
                for (int g = 0; g < 4; ++g) {
                    const float dv = acc[f][g][reg];
                    if (dv > thr) {
                        const int slot = atomicAdd(&cnts[r], 1);
                        if (slot < CAP) {
                            const unsigned int ub =
                                __builtin_bit_cast(unsigned int, fmaxf(dv, 0.0f));
                            cand[(size_t)(row0 + r) * CAP + slot] =
                                (ub & 0xFFFFF000u) |
                                (unsigned int)(c0 + wc * 64 + g * 16 + lm);
                        }
                    }
                }
            }
        }
        // drain global stores (they share vmcnt) so per-chunk counts stay valid
        VM0();
    }
    __syncthreads();
    if (t < P1_BM) cnt_out[row0 + t] = (cnts[t] > CAP) ? -1 : cnts[t];
}

// ---------------------------------------------------------------- kernel P2 (fused)
// Re-filter stored candidates against the FINAL max dot (present among the
// stored keys), stage surviving emb rows into LDS via async global_load_lds
// (all issues back-to-back, ONE vmcnt(0) -- single latency round), then run
// the exact np-semantics re-rank from LDS: dist = fl(fl(sx-2*dot)+se),
// dot = sequential fp32 FMA chain (validated R5/R6). The winner's slot is
// carried through the argmin so the quantized row is read back from LDS
// (no second global gather). Writes quantized + idx + per-row loss partial.
// One wave per row.
__global__ __launch_bounds__(256, 4)
void pass2_kernel(const float* __restrict__ x, const float* __restrict__ emb,
                  const float* __restrict__ sx, const float* __restrict__ se,
                  const unsigned int* __restrict__ cand, const int* __restrict__ cnt,
                  float* __restrict__ out, float* __restrict__ partial) {
    __shared__ float4 xsh[4][64];
    __shared__ float4 esh[4][NS][64];     // staged survivor rows (1 KB each, linear)
    const int w = threadIdx.x >> 6, lane = threadIdx.x & 63;
    const int row = blockIdx.x * 4 + w;
    const int n = cnt[row];
    const float sxr = sx[row];
    const float4* emb4 = (const float4*)emb;

    const float4 myx = ((const float4*)(x + (size_t)row * DIMD))[lane];
    xsh[w][lane] = myx;
    const float4* xs4 = &xsh[w][0];

    float bestd = INFINITY;
    int   bestc = 0x7fffffff;
    int   wslot = 0x7fffffff;

    if (n >= 1 && n <= CAP) {
        float dtil = -INFINITY;
        int   code = 0;
        if (lane < n) {
            const unsigned int word = cand[(size_t)row * CAP + lane];
            dtil = __builtin_bit_cast(float, word & 0xFFFFF000u);
            code = (int)(word & 0xFFFu);
        }
        // wave max of stored (truncated) dots == final max - O(2.5e-6)
        float mx = dtil;
        #pragma unroll
        for (int off = 1; off < 64; off <<= 1)
            mx = fmaxf(mx, __shfl_xor(mx, off, 64));
        const bool active = (lane < n) && (dtil > mx - TAU2B);
        const unsigned long long mask = __ballot(active);
        const int nact = __popcll(mask);
        const int slot = __popcll(mask & ((1ull << lane) - 1ull));
        // async-stage up to NS surviving rows: issue all, wait once
        unsigned long long mm = mask;
        const int ns = nact < NS ? nact : NS;
        for (int i = 0; i < ns; ++i) {
            const int li = __ffsll(mm) - 1;
            mm &= mm - 1;
            const int bc = __shfl(code, li, 64);
            gload_lds16(emb4 + (size_t)bc * 64 + lane, &esh[w][i][0]);
        }
        VM0();
        if (active) {
            float a = 0.0f;
            if (slot < NS) {
                const float4* ep4 = &esh[w][slot][0];
                #pragma unroll
                for (int d4 = 0; d4 < DIMD / 4; ++d4) {
                    const float4 ev = ep4[d4];
                    const float4 xv = xs4[d4];
                    a = fmaf(xv.x, ev.x, a);
                    a = fmaf(xv.y, ev.y, a);
                    a = fmaf(xv.z, ev.z, a);
                    a = fmaf(xv.w, ev.w, a);
                }
            } else {  // rare: >NS survivors, read from global
                const float4* ep4 = emb4 + (size_t)code * 64;
                #pragma unroll
                for (int d4 = 0; d4 < DIMD / 4; ++d4) {
                    const float4 ev = ep4[d4];
                    const float4 xv = xs4[d4];
                    a = fmaf(xv.x, ev.x, a);
                    a = fmaf(xv.y, ev.y, a);
                    a = fmaf(xv.z, ev.z, a);
                    a = fmaf(xv.w, ev.w, a);
                }
            }
            const float t1 = sxr - 2.0f * a;   // fl(sx - 2*dot)
            bestd = t1 + se[code];             // fl(t1 + se)
            bestc = code;
            wslot = slot;
        }
    } else {
        // overflow / safety fallback: full exact scan (ascending per lane)
        for (int c = lane; c < KCODES; c += 64) {
            const float* ep = emb + (size_t)c * DIMD;
            float a = 0.0f;
            for (int d4 = 0; d4 < DIMD / 4; ++d4) {
                const float4 xv = xs4[d4];
                const float4 ev = ((const float4*)ep)[d4];
                a = fmaf(xv.x, ev.x, a);
                a = fmaf(xv.y, ev.y, a);
                a = fmaf(xv.z, ev.z, a);
                a = fmaf(xv.w, ev.w, a);
            }
            const float t1 = sxr - 2.0f * a;
            const float dd = t1 + se[c];
            if (dd < bestd || (dd == bestd && c < bestc)) { bestd = dd; bestc = c; }
        }
    }
    // wave argmin, lexicographic (value, code): np first-occurrence semantics
    #pragma unroll
    for (int off = 32; off > 0; off >>= 1) {
        const float od = __shfl_down(bestd, off, 64);
        const int   oc = __shfl_down(bestc, off, 64);
        const int   os = __shfl_down(wslot, off, 64);
        if (od < bestd || (od == bestd && oc < bestc)) {
            bestd = od; bestc = oc; wslot = os;
        }
    }
    bestc = __shfl(bestc, 0, 64);   // broadcast winner
    wslot = __shfl(wslot, 0, 64);

    // fused epilogue: quantized row (from LDS when staged), idx, loss partial
    const float4 e4 = (wslot < NS) ? esh[w][wslot][lane]
                                   : emb4[(size_t)bestc * 64 + lane];
    ((float4*)(out + (size_t)row * DIMD))[lane] = e4;
    const float dx = e4.x - myx.x, dy = e4.y - myx.y,
                dz = e4.z - myx.z, dw = e4.w - myx.w;
    float s = dx * dx + dy * dy + dz * dz + dw * dw;
    #pragma unroll
    for (int off = 32; off > 0; off >>= 1) s += __shfl_down(s, off, 64);
    if (lane == 0) {
        partial[row] = s;
        out[QN + 1 + row] = (float)bestc;
    }
}

// ---------------------------------------------------------------- kernel L
// reduce 65536 per-row fp32 partials -> loss (LDS tree, double accum)
__global__ void loss_reduce_kernel(const float* __restrict__ partial, float* __restrict__ out) {
    const int t = threadIdx.x;           // 256 threads, 1 block
    double s = 0.0;
    for (int i = t; i < NROWS; i += 256) s += (double)partial[i];
    __shared__ double tsum[256];
    tsum[t] = s;
    __syncthreads();
    #pragma unroll
    for (int off = 128; off > 0; off >>= 1) {
        if (t < off) tsum[t] += tsum[t + off];
        __syncthreads();
    }
    if (t == 0) out[QN] = (float)(tsum[0] * (1.25 / (double)QN));
}

// ---------------------------------------------------------------- launcher
extern "C" void kernel_launch(void* const* d_in, const int* in_sizes, int n_in,
                              void* d_out, int out_size, void* d_ws, size_t ws_size,
                              hipStream_t stream) {
    const float* x   = (const float*)d_in[0];   // [65536, 256]
    const float* emb = (const float*)d_in[1];   // [4096, 256]
    float* out = (float*)d_out;                 // q[16777216] | loss[1] | idx[65536]

    char* ws = (char*)d_ws;
    unsigned short* embh = (unsigned short*)ws;           ws += (size_t)KCODES * DIMD * 2; // 2 MB
    float* sx  = (float*)ws;                              ws += (size_t)NROWS * 4;         // 256 KB
    float* se  = (float*)ws;                              ws += (size_t)KCODES * 4;        // 16 KB
    unsigned int* cand = (unsigned int*)ws;               ws += (size_t)NROWS * CAP * 4;   // 12.6 MB
    int*   cnt  = (int*)ws;                               ws += (size_t)NROWS * 4;         // 256 KB
    float* partial = (float*)ws;                                                           // 256 KB

    conv_emb_kernel<<<KCODES * DIMD / 4 / 256, 256, 0, stream>>>(emb, embh);
    sx_kernel<<<NROWS / 32, 256, 0, stream>>>(x, sx);
    se_kernel<<<KCODES / 32, 256, 0, stream>>>(emb, se);
    pass1_kernel<<<NROWS / P1_BM, 256, 0, stream>>>(x, embh, cand, cnt);
    pass2_kernel<<<NROWS / 4, 256, 0, stream>>>(x, emb, sx, se, cand, cnt, out, partial);
    loss_reduce_kernel<<<1, 256, 0, stream>>>(partial, out);
}